// Round 1
// baseline (4423.102 us; speedup 1.0000x reference)
//
#include <hip/hip_runtime.h>
#include <hip/hip_bf16.h>
#include <math.h>

#define N_NODES 100000
#define N_EDGES 3200000
#define D 64
#define NUM_RELS 20
#define HID_ATTR 32
#define OUT_ATTR 10

// One wave (64 lanes) per edge: msg[o] = sum_d X[src][d] * W[r][d*64+o]
// Lane o holds X[src][o]; broadcast d-th element via shuffle.
// relu_in: apply relu to X at load (layer-2 reads pre-activation agg1).
__global__ void edge_kernel(const float* __restrict__ X,
                            const float* __restrict__ W,
                            const int* __restrict__ src,
                            const int* __restrict__ dst,
                            const int* __restrict__ etype,
                            float* __restrict__ agg,
                            int n_edges, int relu_in) {
    int gwave = (blockIdx.x * blockDim.x + threadIdx.x) >> 6;
    int lane = threadIdx.x & 63;
    if (gwave >= n_edges) return;

    int s = src[gwave];
    int d = dst[gwave];
    int r = etype[gwave];

    float hv = X[(long)s * D + lane];
    if (relu_in) hv = fmaxf(hv, 0.0f);

    const float* Wr = W + (long)r * (D * D);
    float acc = 0.0f;
#pragma unroll
    for (int k = 0; k < D; ++k) {
        float hk = __shfl(hv, k, 64);
        acc = fmaf(hk, Wr[k * D + lane], acc);
    }
    atomicAdd(&agg[(long)d * D + lane], acc);
}

// Column sums of h2 [n, 64] -> g[64] (g pre-zeroed). Block-local LDS reduce,
// then one atomic per column per block.
__global__ void colsum_kernel(const float* __restrict__ h2,
                              float* __restrict__ g, int n) {
    __shared__ float s[256];
    int tid = threadIdx.x;
    int col = tid & 63;
    int rowgrp = (blockIdx.x * blockDim.x + tid) >> 6;   // global row group
    int nrowgrp = (gridDim.x * blockDim.x) >> 6;
    float acc = 0.0f;
    for (int row = rowgrp; row < n; row += nrowgrp)
        acc += h2[(long)row * D + col];
    s[tid] = acc;
    __syncthreads();
    if (tid < 64) {
        acc = s[tid] + s[tid + 64] + s[tid + 128] + s[tid + 192];
        atomicAdd(&g[col], acc);
    }
}

// Single block: a = sigmoid(relu(g/N @ A1 + b1) @ A2 + b2) -> out[10]
__global__ void mlp_kernel(const float* __restrict__ g,
                           const float* __restrict__ A1w,
                           const float* __restrict__ A1b,
                           const float* __restrict__ A2w,
                           const float* __restrict__ A2b,
                           float* __restrict__ out, float invN) {
    __shared__ float a1[HID_ATTR];
    int t = threadIdx.x;
    if (t < HID_ATTR) {
        float acc = A1b[t];
#pragma unroll
        for (int d2 = 0; d2 < D; ++d2)
            acc = fmaf(g[d2] * invN, A1w[d2 * HID_ATTR + t], acc);
        a1[t] = fmaxf(acc, 0.0f);
    }
    __syncthreads();
    if (t < OUT_ATTR) {
        float acc = A2b[t];
#pragma unroll
        for (int j = 0; j < HID_ATTR; ++j)
            acc = fmaf(a1[j], A2w[j * OUT_ATTR + t], acc);
        out[t] = 1.0f / (1.0f + expf(-acc));
    }
}

extern "C" void kernel_launch(void* const* d_in, const int* in_sizes, int n_in,
                              void* d_out, int out_size, void* d_ws, size_t ws_size,
                              hipStream_t stream) {
    const float* h   = (const float*)d_in[0];
    const int* src   = (const int*)d_in[1];
    const int* dst   = (const int*)d_in[2];
    const int* etype = (const int*)d_in[3];
    const float* W1  = (const float*)d_in[4];
    const float* W2  = (const float*)d_in[5];
    const float* A1w = (const float*)d_in[6];
    const float* A1b = (const float*)d_in[7];
    const float* A2w = (const float*)d_in[8];
    const float* A2b = (const float*)d_in[9];

    float* out_h2 = (float*)d_out;                 // [N_NODES, D]
    float* out_a  = out_h2 + (size_t)N_NODES * D;  // [10]

    float* agg1 = (float*)d_ws;                    // [N_NODES, D] = 25.6 MB
    float* gsum = agg1 + (size_t)N_NODES * D;      // [64]

    // zero accumulators (harness poisons d_ws/d_out to 0xAA)
    hipMemsetAsync(agg1, 0, (size_t)N_NODES * D * sizeof(float), stream);
    hipMemsetAsync(gsum, 0, 64 * sizeof(float), stream);
    hipMemsetAsync(out_h2, 0, (size_t)N_NODES * D * sizeof(float), stream);

    // Layer 1: agg1 = segment_sum(W1[r]^T h[src] -> dst)
    {
        int blocks = (N_EDGES + 3) / 4;            // 4 waves per 256-thread block
        edge_kernel<<<blocks, 256, 0, stream>>>(h, W1, src, dst, etype,
                                                agg1, N_EDGES, 0);
    }
    // Layer 2: out_h2 = segment_sum(W2[r]^T relu(agg1)[src] -> dst)
    {
        int blocks = (N_EDGES + 3) / 4;
        edge_kernel<<<blocks, 256, 0, stream>>>(agg1, W2, src, dst, etype,
                                                out_h2, N_EDGES, 1);
    }
    // Readout: column mean + MLP
    colsum_kernel<<<512, 256, 0, stream>>>(out_h2, gsum, N_NODES);
    mlp_kernel<<<1, 64, 0, stream>>>(gsum, A1w, A1b, A2w, A2b,
                                     out_a, 1.0f / (float)N_NODES);
}

// Round 2
// 2335.765 us; speedup vs baseline: 1.8936x; 1.8936x over previous
//
#include <hip/hip_runtime.h>
#include <hip/hip_bf16.h>
#include <math.h>

#define N_NODES 100000
#define N_EDGES 3200000
#define D 64
#define NUM_RELS 20
#define HID_ATTR 32
#define OUT_ATTR 10

#define SORT_BLOCKS 12500          // N_EDGES / 256
#define EPB 128                    // edges per block in rel_edge_kernel
#define MAX_DBLOCKS 25024          // >= N_EDGES/EPB + NUM_RELS
#define EPW 8                      // edges per wave-group

// ---------------- counting sort by relation ----------------

__global__ void sort_hist(const int* __restrict__ etype, int* __restrict__ blkcnt) {
    __shared__ int h[NUM_RELS];
    int t = threadIdx.x;
    if (t < NUM_RELS) h[t] = 0;
    __syncthreads();
    int e = blockIdx.x * 256 + t;
    atomicAdd(&h[etype[e]], 1);
    __syncthreads();
    if (t < NUM_RELS) blkcnt[blockIdx.x * NUM_RELS + t] = h[t];
}

// single block: column prefix sums, relation offsets, block map
__global__ void sort_phase2(const int* __restrict__ blkcnt, int* __restrict__ blkbase,
                            int* __restrict__ reloff,
                            int* __restrict__ bmap_rel, int* __restrict__ bmap_off) {
    const int NB = SORT_BLOCKS, STR = 12, CHUNK = 1042;  // 12*1042 >= 12500
    __shared__ int stripesum[NUM_RELS][STR];
    __shared__ int total[NUM_RELS];
    __shared__ int off[NUM_RELS + 1];
    __shared__ int blkpfx[NUM_RELS + 1];
    int t = threadIdx.x;
    int r = t / STR, j = t % STR;
    if (t < NUM_RELS * STR) {
        int b0 = j * CHUNK, b1 = min(NB, b0 + CHUNK);
        int s = 0;
        for (int b = b0; b < b1; ++b) s += blkcnt[b * NUM_RELS + r];
        stripesum[r][j] = s;
    }
    __syncthreads();
    if (t < NUM_RELS) {
        int s = 0;
        for (int j2 = 0; j2 < STR; ++j2) {
            int v = stripesum[t][j2]; stripesum[t][j2] = s; s += v;
        }
        total[t] = s;
    }
    __syncthreads();
    if (t == 0) {
        int s = 0;
        for (int rr = 0; rr < NUM_RELS; ++rr) { off[rr] = s; s += total[rr]; }
        off[NUM_RELS] = s;
        s = 0;
        for (int rr = 0; rr < NUM_RELS; ++rr) {
            blkpfx[rr] = s; s += (total[rr] + EPB - 1) / EPB;
        }
        blkpfx[NUM_RELS] = s;
    }
    __syncthreads();
    if (t < NUM_RELS + 1) reloff[t] = off[t];
    if (t < NUM_RELS * STR) {
        int b0 = j * CHUNK, b1 = min(NB, b0 + CHUNK);
        int s = stripesum[r][j];
        for (int b = b0; b < b1; ++b) {
            blkbase[b * NUM_RELS + r] = s;
            s += blkcnt[b * NUM_RELS + r];
        }
    }
    __syncthreads();
    int totblk = blkpfx[NUM_RELS];
    for (int i = t; i < totblk; i += 256) {
        int rr = 0;
        while (!(i >= blkpfx[rr] && i < blkpfx[rr + 1])) ++rr;
        bmap_rel[i] = rr;
        bmap_off[i] = off[rr] + (i - blkpfx[rr]) * EPB;
    }
}

__global__ void sort_scatter(const int* __restrict__ src, const int* __restrict__ dst,
                             const int* __restrict__ etype,
                             const int* __restrict__ blkbase, const int* __restrict__ reloff,
                             int* __restrict__ ssrc, int* __restrict__ sdst) {
    __shared__ int cur[NUM_RELS];
    int t = threadIdx.x;
    if (t < NUM_RELS) cur[t] = reloff[t] + blkbase[blockIdx.x * NUM_RELS + t];
    __syncthreads();
    int e = blockIdx.x * 256 + t;
    int r = etype[e];
    int pos = atomicAdd(&cur[r], 1);
    ssrc[pos] = src[e];
    sdst[pos] = dst[e];
}

// ---------------- per-relation edge transform + scatter-add ----------------
// One block = 128 edges of a single relation. W[r] transposed into LDS
// (row stride 68 floats: 16B-aligned, conflict-free ds_read_b128).
// Wave handles 8 edges at a time; x[e][k] is wave-uniform -> SGPR loads.
__global__ __launch_bounds__(256) void rel_edge_kernel(
    const float* __restrict__ X, const float* __restrict__ W,
    const int* __restrict__ ssrc, const int* __restrict__ sdst,
    const int* __restrict__ bmap_rel, const int* __restrict__ bmap_off,
    const int* __restrict__ reloff, float* __restrict__ agg) {
    int r = bmap_rel[blockIdx.x];
    if (r < 0) return;
    __shared__ float Wt[64 * 68];
    const float* Wr = W + (size_t)r * (D * D);
    for (int i = threadIdx.x; i < D * D; i += 256) {
        int k = i >> 6, o = i & 63;
        Wt[o * 68 + k] = Wr[i];
    }
    __syncthreads();
    int wave = threadIdx.x >> 6, lane = threadIdx.x & 63;
    int base = bmap_off[blockIdx.x];
    int end = reloff[r + 1];
    for (int it = 0; it < EPB / (4 * EPW); ++it) {
        int e0 = base + (it * 4 + wave) * EPW;
        int nval = end - e0;
        if (nval <= 0) continue;
        if (nval > EPW) nval = EPW;
        int se[EPW], de[EPW];
#pragma unroll
        for (int e = 0; e < EPW; ++e) {
            int idx = e0 + (e < nval ? e : nval - 1);
            se[e] = __builtin_amdgcn_readfirstlane(ssrc[idx]);
            de[e] = sdst[idx];
        }
        float acc[EPW];
#pragma unroll
        for (int e = 0; e < EPW; ++e) acc[e] = 0.0f;
#pragma unroll
        for (int kb = 0; kb < 16; ++kb) {
            float4 wv = *(const float4*)(&Wt[lane * 68 + kb * 4]);
#pragma unroll
            for (int e = 0; e < EPW; ++e) {
                float4 xv = *(const float4*)(X + (size_t)se[e] * D + kb * 4);
                acc[e] = fmaf(xv.x, wv.x, acc[e]);
                acc[e] = fmaf(xv.y, wv.y, acc[e]);
                acc[e] = fmaf(xv.z, wv.z, acc[e]);
                acc[e] = fmaf(xv.w, wv.w, acc[e]);
            }
        }
        for (int e = 0; e < nval; ++e)
            atomicAdd(&agg[(size_t)de[e] * D + lane], acc[e]);
    }
}

__global__ void relu_kernel(float* __restrict__ x, int n4) {
    int i = blockIdx.x * blockDim.x + threadIdx.x;
    if (i < n4) {
        float4 v = ((float4*)x)[i];
        v.x = fmaxf(v.x, 0.0f); v.y = fmaxf(v.y, 0.0f);
        v.z = fmaxf(v.z, 0.0f); v.w = fmaxf(v.w, 0.0f);
        ((float4*)x)[i] = v;
    }
}

// ---------------- readout ----------------

__global__ void colsum_kernel(const float* __restrict__ h2,
                              float* __restrict__ g, int n) {
    __shared__ float s[256];
    int tid = threadIdx.x;
    int col = tid & 63;
    int rowgrp = (blockIdx.x * blockDim.x + tid) >> 6;
    int nrowgrp = (gridDim.x * blockDim.x) >> 6;
    float acc = 0.0f;
    for (int row = rowgrp; row < n; row += nrowgrp)
        acc += h2[(size_t)row * D + col];
    s[tid] = acc;
    __syncthreads();
    if (tid < 64) {
        acc = s[tid] + s[tid + 64] + s[tid + 128] + s[tid + 192];
        atomicAdd(&g[col], acc);
    }
}

__global__ void mlp_kernel(const float* __restrict__ g,
                           const float* __restrict__ A1w,
                           const float* __restrict__ A1b,
                           const float* __restrict__ A2w,
                           const float* __restrict__ A2b,
                           float* __restrict__ out, float invN) {
    __shared__ float a1[HID_ATTR];
    int t = threadIdx.x;
    if (t < HID_ATTR) {
        float acc = A1b[t];
#pragma unroll
        for (int d2 = 0; d2 < D; ++d2)
            acc = fmaf(g[d2] * invN, A1w[d2 * HID_ATTR + t], acc);
        a1[t] = fmaxf(acc, 0.0f);
    }
    __syncthreads();
    if (t < OUT_ATTR) {
        float acc = A2b[t];
#pragma unroll
        for (int j = 0; j < HID_ATTR; ++j)
            acc = fmaf(a1[j], A2w[j * OUT_ATTR + t], acc);
        out[t] = 1.0f / (1.0f + expf(-acc));
    }
}

// ---------------- launch ----------------

extern "C" void kernel_launch(void* const* d_in, const int* in_sizes, int n_in,
                              void* d_out, int out_size, void* d_ws, size_t ws_size,
                              hipStream_t stream) {
    const float* h   = (const float*)d_in[0];
    const int* src   = (const int*)d_in[1];
    const int* dst   = (const int*)d_in[2];
    const int* etype = (const int*)d_in[3];
    const float* W1  = (const float*)d_in[4];
    const float* W2  = (const float*)d_in[5];
    const float* A1w = (const float*)d_in[6];
    const float* A1b = (const float*)d_in[7];
    const float* A2w = (const float*)d_in[8];
    const float* A2b = (const float*)d_in[9];

    float* out_h2 = (float*)d_out;                  // [N_NODES, D]
    float* out_a  = out_h2 + (size_t)N_NODES * D;   // [10]

    // workspace layout (all 4B elems)
    float* agg1   = (float*)d_ws;                   // 6.4M
    float* gsum   = agg1 + (size_t)N_NODES * D;     // 64
    int* blkcnt   = (int*)(gsum + 64);              // 250000
    int* blkbase  = blkcnt + SORT_BLOCKS * NUM_RELS;// 250000
    int* reloff   = blkbase + SORT_BLOCKS * NUM_RELS; // 21 (pad to 32)
    int* bmap_rel = reloff + 32;                    // 25024
    int* bmap_off = bmap_rel + MAX_DBLOCKS;         // 25024
    int* ssrc     = bmap_off + MAX_DBLOCKS;         // 3.2M
    int* sdst     = ssrc + N_EDGES;                 // 3.2M

    hipMemsetAsync(agg1, 0, (size_t)N_NODES * D * sizeof(float), stream);
    hipMemsetAsync(gsum, 0, 64 * sizeof(float), stream);
    hipMemsetAsync(out_h2, 0, (size_t)N_NODES * D * sizeof(float), stream);
    hipMemsetAsync(bmap_rel, 0xFF, MAX_DBLOCKS * sizeof(int), stream);

    // counting sort by relation
    sort_hist<<<SORT_BLOCKS, 256, 0, stream>>>(etype, blkcnt);
    sort_phase2<<<1, 256, 0, stream>>>(blkcnt, blkbase, reloff, bmap_rel, bmap_off);
    sort_scatter<<<SORT_BLOCKS, 256, 0, stream>>>(src, dst, etype, blkbase, reloff,
                                                  ssrc, sdst);

    // layer 1
    rel_edge_kernel<<<MAX_DBLOCKS, 256, 0, stream>>>(h, W1, ssrc, sdst,
                                                     bmap_rel, bmap_off, reloff, agg1);
    // h1 = relu(agg1) in place
    relu_kernel<<<(N_NODES * D / 4 + 255) / 256, 256, 0, stream>>>(agg1, N_NODES * D / 4);
    // layer 2
    rel_edge_kernel<<<MAX_DBLOCKS, 256, 0, stream>>>(agg1, W2, ssrc, sdst,
                                                     bmap_rel, bmap_off, reloff, out_h2);

    // readout
    colsum_kernel<<<512, 256, 0, stream>>>(out_h2, gsum, N_NODES);
    mlp_kernel<<<1, 64, 0, stream>>>(gsum, A1w, A1b, A2w, A2b,
                                     out_a, 1.0f / (float)N_NODES);
}